// Round 13
// baseline (106.496 us; speedup 1.0000x reference)
//
#include <hip/hip_runtime.h>

// LandmarkLoss, round 24 = R23 with compile fixes. B=4, N=200000, K=64.
// R23 failed to compile: __builtin_amdgcn_writelane undeclared on this ROCm.
// Fixes: (1) writelane -> per-lane conditional select (rs from readlane(63)
// is wave-uniform; g2pacc = (l31==i) ? rs : g2pacc, one v_cndmask per
// compile-time i); (2) DPP reduce corrected to the canonical lane-63
// sequence row_shr:1/2/4/8 + row_bcast:15/31 (R23 draft used row_shl, wrong
// direction); old = FLT_MAX bits + bound_ctrl=false -> shifted-out lanes
// contribute the min identity; (3) (void)hipMemsetAsync.
// Theory under test (unchanged): every falsified bottleneck theory
// (R13/14/19/20) kept per-iteration lgkm/DS traffic. This inner loop has
// ZERO DS ops and ZERO lgkm waits -- targets via readlane from registers,
// per-target g2p via pure-VALU DPP reduce, each wave owning its 32 targets
// exclusively (g2pLDS + cross-wave combine deleted). If the ~300cyc/iter
// exposure is lgkm-borne it disappears (main ~14-17us); if the law survives
// a pure-VALU loop, the limiter is issue-bound -> revert R22 and close.
// Unchanged: pair count, K-split 32/32, P=4, 3128 blocks x 128thr, early
// point loads, unconditional tC load, packed-fp32 dot pairs, key-packed
// top-2 + one-time merge, x16 replicated accumulators, separate finalize.

constexpr int KT = 64;
constexpr int P  = 4;
constexpr int NREP = 16;
constexpr float DIST_THRESH = 0.1f;
constexpr float W_DIST    = 0.05f;
constexpr float W_CHAMFER = 0.05f;
constexpr float W_SEP     = 0.0005f;
constexpr float PT_SENT = -1e18f;  // dummy-point sentinel (tail lanes)
constexpr float TG_SENT = -1e18f;  // invalid-target sentinel
constexpr float BIGF  = 3.0e38f;
constexpr float WBIAS = 16.0f;     // |t|^2 + WBIAS in T.w keeps valid keys > 0

typedef float f2 __attribute__((ext_vector_type(2)));

__device__ __forceinline__ unsigned umin_(unsigned a, unsigned b) { return a < b ? a : b; }
__device__ __forceinline__ unsigned umax_(unsigned a, unsigned b) { return a > b ? a : b; }

__device__ __forceinline__ f2 pk_fma(f2 a, f2 b, f2 c) {
#if __has_builtin(__builtin_elementwise_fma)
    return __builtin_elementwise_fma(a, b, c);
#else
    f2 r; r.x = fmaf(a.x, b.x, c.x); r.y = fmaf(a.y, b.y, c.y); return r;
#endif
}

// 64-lane min over non-negative float bits, pure VALU (DPP), result in lane 63.
// Canonical: row_shr:1/2/4/8 fold within each 16-lane row toward lane 15/31/47/63;
// row_bcast:15 folds row->next-row; row_bcast:31 folds half->upper half.
// old = FLT_MAX bits with bound_ctrl=false: invalid source lanes yield identity.
__device__ __forceinline__ unsigned dpp_umin64(unsigned v) {
    unsigned t;
    t = (unsigned)__builtin_amdgcn_update_dpp(0x7F7FFFFF, (int)v, 0x111, 0xF, 0xF, false); v = umin_(v, t); // row_shr:1
    t = (unsigned)__builtin_amdgcn_update_dpp(0x7F7FFFFF, (int)v, 0x112, 0xF, 0xF, false); v = umin_(v, t); // row_shr:2
    t = (unsigned)__builtin_amdgcn_update_dpp(0x7F7FFFFF, (int)v, 0x114, 0xF, 0xF, false); v = umin_(v, t); // row_shr:4
    t = (unsigned)__builtin_amdgcn_update_dpp(0x7F7FFFFF, (int)v, 0x118, 0xF, 0xF, false); v = umin_(v, t); // row_shr:8
    t = (unsigned)__builtin_amdgcn_update_dpp(0x7F7FFFFF, (int)v, 0x142, 0xF, 0xF, false); v = umin_(v, t); // row_bcast:15
    t = (unsigned)__builtin_amdgcn_update_dpp(0x7F7FFFFF, (int)v, 0x143, 0xF, 0xF, false); v = umin_(v, t); // row_bcast:31
    return v;
}

// ws layout: [0,16384) g2p replicas rep*256+b*64+k (encode ~bits(g), init 0);
//            [16384,17408) sums replicas rep*16 + c*4 + b (float, init 0)
__global__ __launch_bounds__(128, 4)
void landmark_main(const float* __restrict__ C, const float* __restrict__ F,
                   const float* __restrict__ tC, const int* __restrict__ tF,
                   const int* __restrict__ classes, int n_classes, int N,
                   unsigned int* __restrict__ g2p_rep, float* __restrict__ sums_rep)
{
    __shared__ float4   tgtFull[KT];   // epilogue companion-lookup table only
    __shared__ uint4    mK1[64], mK2[64];   // wave A -> B merge (lane-indexed)
    __shared__ float4   mLM[64];

    const int tid   = threadIdx.x;
    const int lane  = tid & 63;
    const int h     = tid >> 6;        // wave: 0 -> targets [0,32), 1 -> [32,64)
    const int l31   = lane & 31;
    const int hi5   = lane >> 5;
    const int blk   = blockIdx.x;
    const int b     = blk & 3;
    const int chunk = blk >> 2;
    const int rep   = chunk & (NREP - 1);

    const float*  Cb = C + (size_t)b * N * 3;
    const float4* Fb = (const float4*)(F + (size_t)b * N * 4);
    const int base = chunk * (64 * P);   // block covers 256 points

    // ---- issue point loads FIRST ----
    float4 rf[P]; float rX[P], rY[P], rZ[P];
    #pragma unroll
    for (int p = 0; p < P; ++p) {
        int n = base + p * 64 + lane;
        int ni = (n < N) ? n : 0;
        rf[p] = Fb[ni];
        rX[p] = Cb[3 * ni + 0];
        rY[p] = Cb[3 * ni + 1];
        rZ[p] = Cb[3 * ni + 2];
    }

    // ---- per-lane target prep (registers; loop needs NO LDS for targets) ----
    // lane j (both 32-halves) holds target (h*32 + (j&31)); tC unconditional.
    const int tgt = (h << 5) | l31;
    int   tfv = tF[b * KT + tgt];
    float tx = tC[(b * KT + tgt) * 3 + 0];
    float ty = tC[(b * KT + tgt) * 3 + 1];
    float tz = tC[(b * KT + tgt) * 3 + 2];
    bool tvalid = false;
    for (int c = 0; c < n_classes; ++c) tvalid = tvalid || (tfv == classes[c]);
    if (!tvalid) { tx = TG_SENT; ty = TG_SENT; tz = TG_SENT; }
    const float4 vT = make_float4(-2.f * tx, -2.f * ty, -2.f * tz,
                                  tx * tx + ty * ty + tz * tz + WBIAS);
    if (hi5 == 0) tgtFull[tgt] = vT;   // staged for epilogue (barrier later)
    const unsigned tbx = __float_as_uint(vT.x);
    const unsigned tby = __float_as_uint(vT.y);
    const unsigned tbz = __float_as_uint(vT.z);
    const unsigned tbw = __float_as_uint(vT.w);

    // ---- process the staged points ----
    f2 pcx[P], pcy[P], pcz[P];
    float ppm[P], ccm[P], f0[P];
    #pragma unroll
    for (int p = 0; p < P; ++p) {
        int n = base + p * 64 + lane;
        bool v = (n < N);
        float4 f4 = rf[p];
        float X = rX[p], Y = rY[p], Z = rZ[p];
        f0[p] = v ? f4.x : 2.0f * DIST_THRESH;
        if (!v) { X = PT_SENT; Y = PT_SENT; Z = PT_SENT; f4.y = f4.z = f4.w = 0.f; }
        float cxv = X + f4.y, cyv = Y + f4.z, czv = Z + f4.w;
        pcx[p] = (f2){X, cxv};
        pcy[p] = (f2){Y, cyv};
        pcz[p] = (f2){Z, czv};
        ppm[p] = fmaf(Z, Z, fmaf(Y, Y, X * X)) - WBIAS;
        ccm[p] = fmaf(czv, czv, fmaf(cyv, cyv, cxv * cxv)) - WBIAS;
    }

    unsigned k1[P], k2[P];
    float lmin[P];
    #pragma unroll
    for (int p = 0; p < P; ++p) { k1[p] = 0xFFFFFFFFu; k2[p] = 0xFFFFFFFFu; lmin[p] = BIGF; }

    unsigned g2pacc = 0x7F7FFFFFu;     // slot-lane i (l31==i): min for target i|hb
    const unsigned hb = (unsigned)(h << 5);

    // ---- zero-LDS inner loop: 32 uniform-target iterations ----
    #pragma unroll 8
    for (int i = 0; i < 32; ++i) {
        const float Txs = __uint_as_float((unsigned)__builtin_amdgcn_readlane((int)tbx, i));
        const float Tys = __uint_as_float((unsigned)__builtin_amdgcn_readlane((int)tby, i));
        const float Tzs = __uint_as_float((unsigned)__builtin_amdgcn_readlane((int)tbz, i));
        const float Tws = __uint_as_float((unsigned)__builtin_amdgcn_readlane((int)tbw, i));
        const unsigned tk = (unsigned)i | hb;
        const f2 Tx = {Txs, Txs}, Ty = {Tys, Tys}, Tz = {Tzs, Tzs}, Tw = {Tws, Tws};
        float av[P];
        #pragma unroll
        for (int p = 0; p < P; ++p) {
            f2 w2 = pk_fma(pcx[p], Tx, pk_fma(pcy[p], Ty, pk_fma(pcz[p], Tz, Tw)));
            unsigned key = (__float_as_uint(w2.x) & 0xFFFFFFC0u) | tk;
            unsigned hi = umax_(k1[p], key);
            k1[p] = umin_(k1[p], key);
            k2[p] = umin_(k2[p], hi);
            lmin[p] = fminf(lmin[p], w2.y);
            av[p] = w2.y + ccm[p];
        }
        float dl = fmaxf(fminf(fminf(av[0], av[1]), fminf(av[2], av[3])), 0.f);
        unsigned red = dpp_umin64(__float_as_uint(dl));          // VALU only
        unsigned rs = (unsigned)__builtin_amdgcn_readlane((int)red, 63);  // wave min (uniform)
        g2pacc = (l31 == i) ? rs : g2pacc;                       // v_cndmask, no writelane
    }

    // ---- publish g2p: each wave owns its half; slot-lanes hold the minima ----
    if (hi5 == 0)   // bits >= 0; ~bits monotone decreasing -> atomicMax == min
        atomicMax(&g2p_rep[rep * 256 + b * 64 + tgt], ~g2pacc);

    // ---- wave A publishes its per-point state for the merge ----
    if (h == 0) {
        mK1[lane] = make_uint4(k1[0], k1[1], k1[2], k1[3]);
        mK2[lane] = make_uint4(k2[0], k2[1], k2[2], k2[3]);
        mLM[lane] = make_float4(lmin[0], lmin[1], lmin[2], lmin[3]);
    }
    __syncthreads();   // orders tgtFull staging + merge publish

    if (h == 1) {
        // ---- merge halves + epilogue (wave B only) ----
        uint4 A1 = mK1[lane], A2 = mK2[lane];
        float4 AL = mLM[lane];
        const unsigned a1v[P] = {A1.x, A1.y, A1.z, A1.w};
        const unsigned a2v[P] = {A2.x, A2.y, A2.z, A2.w};
        const float    alv[P] = {AL.x, AL.y, AL.z, AL.w};

        float dist_acc = 0.f, p2g_acc = 0.f, sep_acc = 0.f;
        #pragma unroll
        for (int p = 0; p < P; ++p) {
            unsigned m1 = umin_(a1v[p], k1[p]);
            unsigned m2 = umin_(umax_(a1v[p], k1[p]), umin_(a2v[p], k2[p]));
            float lm = fminf(alv[p], lmin[p]);
            float keyf1 = __uint_as_float(m1 & 0xFFFFFFC0u);
            float mind = sqrtf(fmaxf(keyf1 + ppm[p], 0.f));
            bool pm = mind < DIST_THRESH;            // false for dummy (ppm huge)
            float tgtv = fminf(mind, 2.0f * DIST_THRESH);
            float diff = f0[p] - tgtv;
            float ad = fabsf(diff);
            dist_acc += (ad < 1.0f) ? 0.5f * diff * diff : (ad - 0.5f);
            if (pm) {
                p2g_acc += fmaxf(lm + ccm[p], 0.f);
                int i1 = (int)(m1 & 63u), i2 = (int)(m2 & 63u);
                float4 T1 = tgtFull[i1], T2 = tgtFull[i2];
                float cxv = pcx[p].y, cyv = pcy[p].y, czv = pcz[p].y;
                float l1sq = fmaf(cxv, T1.x, fmaf(cyv, T1.y, fmaf(czv, T1.z, T1.w))) + ccm[p];
                float l2sq = fmaf(cxv, T2.x, fmaf(cyv, T2.y, fmaf(czv, T2.z, T2.w))) + ccm[p];
                sep_acc += sqrtf(fmaxf(l1sq, 0.f) / fmaxf(l2sq, 1e-30f));
            }
        }

        float v0 = dist_acc, v1 = p2g_acc, v2 = sep_acc;
        #pragma unroll
        for (int o = 32; o > 0; o >>= 1) {
            v0 += __shfl_down(v0, o, 64);
            v1 += __shfl_down(v1, o, 64);
            v2 += __shfl_down(v2, o, 64);
        }
        if (lane == 0) {
            float* sb = sums_rep + rep * 16 + b;
            atomicAdd(sb + 0, v0);
            atomicAdd(sb + 4, v1);
            atomicAdd(sb + 8, v2);
        }
    }
}

__global__ void landmark_finalize(const int* __restrict__ tF, const int* __restrict__ classes,
                                  int n_classes, const unsigned int* __restrict__ g2p_rep,
                                  const float* __restrict__ sums_rep, float* __restrict__ out)
{
    __shared__ float lossb[4];
    const int tid = threadIdx.x;          // 256 threads
    const int b = tid >> 6, k = tid & 63;

    int f = tF[b * KT + k];
    bool valid = false;
    for (int c = 0; c < n_classes; ++c) valid = valid || (f == classes[c]);

    unsigned enc = 0;
    for (int r = 0; r < NREP; ++r) enc = umax_(enc, g2p_rep[r * 256 + b * 64 + k]);
    float g  = valid ? __uint_as_float(~enc) : 0.f;
    float nv = valid ? 1.f : 0.f;

    #pragma unroll
    for (int o = 32; o > 0; o >>= 1) {
        g  += __shfl_down(g, o, 64);
        nv += __shfl_down(nv, o, 64);
    }
    if (k == 0) {
        float sd = 0.f, sp = 0.f, ss = 0.f;
        for (int r = 0; r < NREP; ++r) {
            sd += sums_rep[r * 16 + 0 + b];
            sp += sums_rep[r * 16 + 4 + b];
            ss += sums_rep[r * 16 + 8 + b];
        }
        float sep = (nv >= 2.f) ? ss : 0.f;
        lossb[b] = W_DIST * sd + W_CHAMFER * (sp + g) + W_SEP * sep;
    }
    __syncthreads();
    if (tid == 0)
        out[0] = (lossb[0] + lossb[1] + lossb[2] + lossb[3]) * 0.25f;
}

extern "C" void kernel_launch(void* const* d_in, const int* in_sizes, int n_in,
                              void* d_out, int out_size, void* d_ws, size_t ws_size,
                              hipStream_t stream)
{
    const float* C       = (const float*)d_in[0];   // (B,N,3)
    const float* F       = (const float*)d_in[1];   // (B,N,4)
    const float* tC      = (const float*)d_in[2];   // (B,K,3)
    const int*   tF      = (const int*)d_in[3];     // (B,K)
    const int*   classes = (const int*)d_in[4];     // (6,)
    const int n_classes = in_sizes[4];
    const int B = 4;
    const int N = in_sizes[0] / (3 * B);            // 200000

    unsigned int* g2p_rep  = (unsigned int*)d_ws;
    float*        sums_rep = (float*)((char*)d_ws + NREP * 256 * 4);

    (void)hipMemsetAsync(d_ws, 0, NREP * 256 * 4 + NREP * 16 * 4, stream);

    const int cpb = (N + 64 * P - 1) / (64 * P);    // 782 chunks per batch
    landmark_main<<<cpb * 4, 128, 0, stream>>>(C, F, tC, tF, classes, n_classes,
                                               N, g2p_rep, sums_rep);
    landmark_finalize<<<1, 256, 0, stream>>>(tF, classes, n_classes, g2p_rep,
                                             sums_rep, (float*)d_out);
}

// Round 14
// 97.609 us; speedup vs baseline: 1.0910x; 1.0910x over previous
//
#include <hip/hip_runtime.h>

// LandmarkLoss, FINAL = round 18 verbatim (session best: 97.0-97.4us total,
// beats the 97.8us incoming baseline). Re-submitted to lock in after R24's
// zero-LDS experiment regressed (+9us) and falsified the last open theory.
// Complete map of the design space (all by measurement):
//   - in-loop per-target reduction: fire-and-forget ds_min is cheapest
//     (30us) vs ds_bpermute (35, R14), plain-write scatter+reduce (40, R20),
//     pure-VALU DPP+readlane (40, R24). The ~300cyc/iter exposure is
//     pipe-INDEPENDENT (issue/dependence-bound at ~20% VALUBusy).
//   - P=4 optimal (P=2: 40us R13; P=8: 36us R16).
//   - more occupancy doesn't help (R13: 51% occ, slower); fewer/bigger
//     blocks don't help (R12/R15); 3128 blocks optimal.
//   - fused last-block finalize loses ~45ns/block (threadfence+counter tax,
//     R12-R15); separate finalize kernel wins.
//   - chunk-pair pipelining net-worse (R17); symmetric epilogue worse (R21).
//   - R18's wins: double-banked T-prefetch (lgkm FIFO order [R(g+1)][A(g)] --
//     T-reads never drain behind queued atomics), point loads issued before
//     target staging, unconditional tC load (no serial tF->valid->tC chain).
// Timed-region composition: ~43us harness workspace fill (HBM roofline,
// untouchable) + ~30us main + ~12us small dispatches. Main's residual above
// its ~7us VALU floor survived eight falsified theories -- closed.

constexpr int KT = 64;
constexpr int P  = 4;
constexpr int NREP = 16;
constexpr float DIST_THRESH = 0.1f;
constexpr float W_DIST    = 0.05f;
constexpr float W_CHAMFER = 0.05f;
constexpr float W_SEP     = 0.0005f;
constexpr float PT_SENT = -1e18f;  // dummy-point sentinel (tail lanes)
constexpr float TG_SENT = -1e18f;  // invalid-target sentinel
constexpr float BIGF  = 3.0e38f;
constexpr float WBIAS = 16.0f;     // |t|^2 + WBIAS in T.w keeps valid keys > 0

typedef float f2 __attribute__((ext_vector_type(2)));

__device__ __forceinline__ unsigned umin_(unsigned a, unsigned b) { return a < b ? a : b; }
__device__ __forceinline__ unsigned umax_(unsigned a, unsigned b) { return a > b ? a : b; }

__device__ __forceinline__ f2 pk_fma(f2 a, f2 b, f2 c) {
#if __has_builtin(__builtin_elementwise_fma)
    return __builtin_elementwise_fma(a, b, c);
#else
    f2 r; r.x = fmaf(a.x, b.x, c.x); r.y = fmaf(a.y, b.y, c.y); return r;
#endif
}

// ws layout: [0,16384) g2p replicas rep*256+b*64+k (encode ~bits(g), init 0);
//            [16384,17408) sums replicas rep*16 + c*4 + b (float, init 0)
__global__ __launch_bounds__(128, 4)
void landmark_main(const float* __restrict__ C, const float* __restrict__ F,
                   const float* __restrict__ tC, const int* __restrict__ tF,
                   const int* __restrict__ classes, int n_classes, int N,
                   unsigned int* __restrict__ g2p_rep, float* __restrict__ sums_rep)
{
    __shared__ float4   tgtFull[KT];   // staged targets (-2t, |t|^2+WBIAS)
    __shared__ unsigned g2pLDS[KT];    // per-target min bits (float >= 0)
    __shared__ uint4    mK1[64], mK2[64];   // wave A -> B merge (lane-indexed,
    __shared__ float4   mLM[64];            //  16B stride: conflict-free)

    const int tid   = threadIdx.x;
    const int lane  = tid & 63;
    const int h     = tid >> 6;        // wave: 0 -> targets [0,32), 1 -> [32,64)
    const int l31   = lane & 31;
    const int hi5   = lane >> 5;       // within-wave 32-lane phase
    const int blk   = blockIdx.x;
    const int b     = blk & 3;
    const int chunk = blk >> 2;
    const int rep   = chunk & (NREP - 1);

    const float*  Cb = C + (size_t)b * N * 3;
    const float4* Fb = (const float4*)(F + (size_t)b * N * 4);
    const int base = chunk * (64 * P);   // block covers 256 points

    // ---- issue point loads FIRST (latency overlaps target staging) ----
    float4 rf[P]; float rX[P], rY[P], rZ[P];
    #pragma unroll
    for (int p = 0; p < P; ++p) {
        int n = base + p * 64 + lane;
        int ni = (n < N) ? n : 0;
        rf[p] = Fb[ni];
        rX[p] = Cb[3 * ni + 0];
        rY[p] = Cb[3 * ni + 1];
        rZ[p] = Cb[3 * ni + 2];
    }

    // Stage 64 targets: (-2tx,-2ty,-2tz, |t|^2+WBIAS), sentinel if invalid.
    // tC loaded unconditionally -- no serial tF->valid->tC HBM chain.
    if (tid < KT) {
        int f = tF[b * KT + tid];
        float x = tC[(b * KT + tid) * 3 + 0];
        float y = tC[(b * KT + tid) * 3 + 1];
        float z = tC[(b * KT + tid) * 3 + 2];
        bool valid = false;
        for (int c = 0; c < n_classes; ++c) valid = valid || (f == classes[c]);
        if (!valid) { x = TG_SENT; y = TG_SENT; z = TG_SENT; }
        tgtFull[tid] = make_float4(-2.f * x, -2.f * y, -2.f * z,
                                   x * x + y * y + z * z + WBIAS);
        g2pLDS[tid] = 0x7F7FFFFFu;     // FLT_MAX bits
    }
    __syncthreads();

    // ---- process the staged points ----
    f2 pcx[P], pcy[P], pcz[P];         // (raw coord, offset coord) packed pairs
    float ppm[P], ccm[P], f0[P];
    #pragma unroll
    for (int p = 0; p < P; ++p) {
        int n = base + p * 64 + lane;
        bool v = (n < N);
        float4 f4 = rf[p];
        float X = rX[p], Y = rY[p], Z = rZ[p];
        // dummy points: coords -> sentinel; f0 -> 0.2 so dist term cancels.
        f0[p] = v ? f4.x : 2.0f * DIST_THRESH;
        if (!v) { X = PT_SENT; Y = PT_SENT; Z = PT_SENT; f4.y = f4.z = f4.w = 0.f; }
        float cxv = X + f4.y, cyv = Y + f4.z, czv = Z + f4.w;
        pcx[p] = (f2){X, cxv};
        pcy[p] = (f2){Y, cyv};
        pcz[p] = (f2){Z, czv};
        ppm[p] = fmaf(Z, Z, fmaf(Y, Y, X * X)) - WBIAS;
        ccm[p] = fmaf(czv, czv, fmaf(cyv, cyv, cxv * cxv)) - WBIAS;
    }

    // keyf = T.w - 2 p.t (= true pd2 - |p|^2 + WBIAS, > 0 for valid pairs)
    unsigned k1[P], k2[P];
    float lmin[P];
    #pragma unroll
    for (int p = 0; p < P; ++p) { k1[p] = 0xFFFFFFFFu; k2[p] = 0xFFFFFFFFu; lmin[p] = BIGF; }

    // Rotation tk = tkb ^ i: per-iteration bijection within the wave's half;
    // hi5 XOR de-collides the two 32-lane phases' ds_min addresses.
    const unsigned tkb = (unsigned)((l31 ^ (hi5 << 4)) | (h << 5));

    // ---- double-banked inner loop: 8 groups x 4 iterations ----
    float4 Tb[2][4];   // fully-unrolled access only (compile-time indices)
    #pragma unroll
    for (int j = 0; j < 4; ++j) Tb[0][j] = tgtFull[tkb ^ (unsigned)j];

    #pragma unroll
    for (int g = 0; g < 8; ++g) {
        const int cur = g & 1, nxt = cur ^ 1;
        // issue next bank's reads BEFORE this group's compute+atomics:
        // lgkm FIFO order [R(g+1)][A(g)] -> draining for R never waits on A.
        if (g < 7) {
            #pragma unroll
            for (int j = 0; j < 4; ++j)
                Tb[nxt][j] = tgtFull[tkb ^ (unsigned)((g + 1) * 4 + j)];
        }
        #pragma unroll
        for (int j = 0; j < 4; ++j) {
            const unsigned tk = tkb ^ (unsigned)(g * 4 + j);
            const float4 T = Tb[cur][j];
            const f2 Tx = {T.x, T.x}, Ty = {T.y, T.y}, Tz = {T.z, T.z}, Tw = {T.w, T.w};
            float av[P];
            #pragma unroll
            for (int p = 0; p < P; ++p) {
                f2 w2 = pk_fma(pcx[p], Tx, pk_fma(pcy[p], Ty, pk_fma(pcz[p], Tz, Tw)));
                unsigned key = (__float_as_uint(w2.x) & 0xFFFFFFC0u) | tk;
                unsigned hi = umax_(k1[p], key);
                k1[p] = umin_(k1[p], key);
                k2[p] = umin_(k2[p], hi);
                lmin[p] = fminf(lmin[p], w2.y);
                av[p] = w2.y + ccm[p];                // true ld2 for cross-p compare
            }
            float dl = fmaxf(fminf(fminf(av[0], av[1]), fminf(av[2], av[3])), 0.f);
            atomicMin(&g2pLDS[tk], __float_as_uint(dl));  // ds_min_u32, no return
        }
    }

    // ---- wave A publishes its half's per-point state for the merge ----
    if (h == 0) {
        mK1[lane] = make_uint4(k1[0], k1[1], k1[2], k1[3]);
        mK2[lane] = make_uint4(k2[0], k2[1], k2[2], k2[3]);
        mLM[lane] = make_float4(lmin[0], lmin[1], lmin[2], lmin[3]);
    }
    __syncthreads();   // ds_min complete + merge publish visible

    if (h == 0) {
        // g2pLDS holds bits(g), g>=0; ~bits monotone decreasing -> atomicMax == min.
        atomicMax(&g2p_rep[rep * 256 + b * 64 + lane], ~g2pLDS[lane]);
    } else {
        // ---- merge halves + epilogue (wave B only) ----
        uint4 A1 = mK1[lane], A2 = mK2[lane];
        float4 AL = mLM[lane];
        const unsigned a1v[P] = {A1.x, A1.y, A1.z, A1.w};
        const unsigned a2v[P] = {A2.x, A2.y, A2.z, A2.w};
        const float    alv[P] = {AL.x, AL.y, AL.z, AL.w};

        float dist_acc = 0.f, p2g_acc = 0.f, sep_acc = 0.f;
        #pragma unroll
        for (int p = 0; p < P; ++p) {
            unsigned m1 = umin_(a1v[p], k1[p]);
            unsigned m2 = umin_(umax_(a1v[p], k1[p]), umin_(a2v[p], k2[p]));
            float lm = fminf(alv[p], lmin[p]);
            float keyf1 = __uint_as_float(m1 & 0xFFFFFFC0u);
            float mind = sqrtf(fmaxf(keyf1 + ppm[p], 0.f));
            bool pm = mind < DIST_THRESH;            // false for dummy (ppm huge)
            float tgtv = fminf(mind, 2.0f * DIST_THRESH);
            float diff = f0[p] - tgtv;
            float ad = fabsf(diff);
            dist_acc += (ad < 1.0f) ? 0.5f * diff * diff : (ad - 0.5f);
            if (pm) {
                p2g_acc += fmaxf(lm + ccm[p], 0.f);
                int i1 = (int)(m1 & 63u), i2 = (int)(m2 & 63u);
                float4 T1 = tgtFull[i1], T2 = tgtFull[i2];
                float cxv = pcx[p].y, cyv = pcy[p].y, czv = pcz[p].y;
                float l1sq = fmaf(cxv, T1.x, fmaf(cyv, T1.y, fmaf(czv, T1.z, T1.w))) + ccm[p];
                float l2sq = fmaf(cxv, T2.x, fmaf(cyv, T2.y, fmaf(czv, T2.z, T2.w))) + ccm[p];
                sep_acc += sqrtf(fmaxf(l1sq, 0.f) / fmaxf(l2sq, 1e-30f));
            }
        }

        float v0 = dist_acc, v1 = p2g_acc, v2 = sep_acc;
        #pragma unroll
        for (int o = 32; o > 0; o >>= 1) {
            v0 += __shfl_down(v0, o, 64);
            v1 += __shfl_down(v1, o, 64);
            v2 += __shfl_down(v2, o, 64);
        }
        if (lane == 0) {
            float* sb = sums_rep + rep * 16 + b;
            atomicAdd(sb + 0, v0);
            atomicAdd(sb + 4, v1);
            atomicAdd(sb + 8, v2);
        }
    }
}

__global__ void landmark_finalize(const int* __restrict__ tF, const int* __restrict__ classes,
                                  int n_classes, const unsigned int* __restrict__ g2p_rep,
                                  const float* __restrict__ sums_rep, float* __restrict__ out)
{
    __shared__ float lossb[4];
    const int tid = threadIdx.x;          // 256 threads
    const int b = tid >> 6, k = tid & 63;

    int f = tF[b * KT + k];
    bool valid = false;
    for (int c = 0; c < n_classes; ++c) valid = valid || (f == classes[c]);

    unsigned enc = 0;
    for (int r = 0; r < NREP; ++r) enc = umax_(enc, g2p_rep[r * 256 + b * 64 + k]);
    float g  = valid ? __uint_as_float(~enc) : 0.f;
    float nv = valid ? 1.f : 0.f;

    #pragma unroll
    for (int o = 32; o > 0; o >>= 1) {
        g  += __shfl_down(g, o, 64);
        nv += __shfl_down(nv, o, 64);
    }
    if (k == 0) {
        float sd = 0.f, sp = 0.f, ss = 0.f;
        for (int r = 0; r < NREP; ++r) {
            sd += sums_rep[r * 16 + 0 + b];
            sp += sums_rep[r * 16 + 4 + b];
            ss += sums_rep[r * 16 + 8 + b];
        }
        float sep = (nv >= 2.f) ? ss : 0.f;
        lossb[b] = W_DIST * sd + W_CHAMFER * (sp + g) + W_SEP * sep;
    }
    __syncthreads();
    if (tid == 0)
        out[0] = (lossb[0] + lossb[1] + lossb[2] + lossb[3]) * 0.25f;
}

extern "C" void kernel_launch(void* const* d_in, const int* in_sizes, int n_in,
                              void* d_out, int out_size, void* d_ws, size_t ws_size,
                              hipStream_t stream)
{
    const float* C       = (const float*)d_in[0];   // (B,N,3)
    const float* F       = (const float*)d_in[1];   // (B,N,4)
    const float* tC      = (const float*)d_in[2];   // (B,K,3)
    const int*   tF      = (const int*)d_in[3];     // (B,K)
    const int*   classes = (const int*)d_in[4];     // (6,)
    const int n_classes = in_sizes[4];
    const int B = 4;
    const int N = in_sizes[0] / (3 * B);            // 200000

    unsigned int* g2p_rep  = (unsigned int*)d_ws;
    float*        sums_rep = (float*)((char*)d_ws + NREP * 256 * 4);

    (void)hipMemsetAsync(d_ws, 0, NREP * 256 * 4 + NREP * 16 * 4, stream);

    const int cpb = (N + 64 * P - 1) / (64 * P);    // 782 chunks per batch
    landmark_main<<<cpb * 4, 128, 0, stream>>>(C, F, tC, tF, classes, n_classes,
                                               N, g2p_rep, sums_rep);
    landmark_finalize<<<1, 256, 0, stream>>>(tF, classes, n_classes, g2p_rep,
                                             sums_rep, (float*)d_out);
}